// Round 3
// baseline (324.758 us; speedup 1.0000x reference)
//
#include <hip/hip_runtime.h>

// FlowNet correlation: out[b, dy*9+dx, y, x] = (1/256) sum_c x1[b,c,y,x] * x2[b,c,y+dy-4,x+dx-4]
// B=4 C=256 H=W=128, 9x9 displacements, zero padding.
//
// Round-3 design (= round-2 + two changes):
//  - XCD-aware swizzle: the 3 d-group siblings of a tile get bids {base, base+8, base+16}
//    -> same XCD (bid%8 round-robin), temporally adjacent -> x1/x2 reads L2-shared.
//  - x1 register prefetch: next chunk's 4 x1 float4 loaded alongside the x2 prefetch,
//    removing global-load latency from the barrier-to-barrier critical path.
//  - Unchanged: 3 waves/block (one dy per wave), acc[9][4] in regs, x2 staged row-major
//    stride 48 dw (conflict-free b128), double-buffered, one barrier per 4-channel chunk.

#define MD 4
constexpr int Bc = 4, Cc = 256, Hc = 128, Wc = 128;
constexpr int TH = 16, TW = 16;
constexpr int NDY = 3;                  // dy per d-group (one per wave)
constexpr int CC = 4;                   // channels per chunk
constexpr int SROWS = TH + NDY - 1;     // 18 staged rows
constexpr int SCOLS = TW + 2 * MD;      // 24 staged cols
constexpr int RSC = 48;                 // padded row stride (dw); 48 % 32 == 16 -> b128 conflict-free
constexpr int CH_STRIDE = SROWS * RSC;  // 864 dw per channel
constexpr int BUF_DW = CC * CH_STRIDE;  // 3456 dw per buffer
constexpr int NF4 = CC * SROWS * (SCOLS / 4);  // 432 float4 staging slots
constexpr int NTHR = 192;
constexpr int NSLOT = 3;                // ceil(432/192)
constexpr int NK = Cc / CC;             // 64 chunks

__global__ __launch_bounds__(NTHR, 4)
void corr_kernel(const float* __restrict__ x1, const float* __restrict__ x2,
                 float* __restrict__ out)
{
    __shared__ float stg[2 * BUF_DW];   // 27648 B

    const int tid  = threadIdx.x;
    const int w    = tid >> 6;          // wave id = local dy
    const int lane = tid & 63;
    const int gy   = lane >> 2;         // 0..15 tile row
    const int gx   = lane & 3;          // 0..3  col-group (4 px each)

    // ---- XCD-aware swizzle: g-siblings (same tile) differ by +8 in bid -> same XCD ----
    const int bid  = blockIdx.x;
    const int q    = bid / 24;
    const int r    = bid - q * 24;
    const int g    = r >> 3;            // d-group 0..2
    const int t    = q * 8 + (r & 7);   // tile index 0..255
    const int tx = t & 7;
    const int ty = (t >> 3) & 7;
    const int bb = t >> 6;
    const int x0 = tx * TW, y0 = ty * TH;
    const int rowbase = y0 + 3 * g - MD;   // global y of staged row 0

    // ---- hoisted staging slot descriptors (fixed per thread across chunks) ----
    int  s_goff[NSLOT], s_loff[NSLOT];
    bool s_val[NSLOT], s_act[NSLOT];
    #pragma unroll
    for (int s = 0; s < NSLOT; ++s) {
        int idx = tid + s * NTHR;
        bool active = idx < NF4;
        int i2  = active ? idx : 0;
        int cl  = i2 / (SROWS * 6);
        int rem = i2 - cl * (SROWS * 6);
        int rr  = rem / 6;
        int gc  = rem - rr * 6;
        int yy  = rowbase + rr;
        int xx  = x0 - 4 + 4 * gc;          // multiple of 4: float4 all-valid or all-invalid
        s_act[s]  = active;
        s_val[s]  = active && ((unsigned)yy < (unsigned)Hc) && ((unsigned)xx < (unsigned)(Wc - 3));
        s_goff[s] = cl * (Hc * Wc) + yy * Wc + xx;
        s_loff[s] = cl * CH_STRIDE + rr * RSC + 4 * gc;
    }

    const float* x2b = x2 + (size_t)bb * Cc * Hc * Wc;
    const float* x1b = x1 + (((size_t)bb * Cc) * Hc + (y0 + gy)) * Wc + x0 + 4 * gx;

    float acc[9][4];
    #pragma unroll
    for (int dx = 0; dx < 9; ++dx)
        #pragma unroll
        for (int p = 0; p < 4; ++p) acc[dx][p] = 0.f;

    const float4 f40 = make_float4(0.f, 0.f, 0.f, 0.f);
    float4 nf[NSLOT];
    float4 a1[CC], a1n[CC];

    // ---- prologue: stage chunk 0 (x2 -> LDS buffer 0, x1 -> regs) ----
    #pragma unroll
    for (int s = 0; s < NSLOT; ++s) {
        nf[s] = f40;
        if (s_val[s]) nf[s] = *(const float4*)(x2b + s_goff[s]);
    }
    #pragma unroll
    for (int cl = 0; cl < CC; ++cl)
        a1[cl] = *(const float4*)(x1b + cl * (Hc * Wc));
    #pragma unroll
    for (int s = 0; s < NSLOT; ++s)
        if (s_act[s]) *(float4*)(&stg[s_loff[s]]) = nf[s];

    for (int k = 0; k < NK; ++k) {
        const int pb = k & 1;
        // issue global prefetch for chunk k+1 (x2 slots + x1 tile), overlapped with compute
        if (k + 1 < NK) {
            const int gof = (k + 1) * CC * Hc * Wc;
            #pragma unroll
            for (int s = 0; s < NSLOT; ++s) {
                nf[s] = f40;
                if (s_val[s]) nf[s] = *(const float4*)(x2b + gof + s_goff[s]);
            }
            #pragma unroll
            for (int cl = 0; cl < CC; ++cl)
                a1n[cl] = *(const float4*)(x1b + (gof + cl * (Hc * Wc)));
        }
        __syncthreads();   // chunk k's buffer fully written; prev buffer's readers done
        // ---- compute chunk k ----
        #pragma unroll
        for (int cl = 0; cl < CC; ++cl) {
            const float4 a4 = a1[cl];
            const float* rowp = &stg[pb * BUF_DW + cl * CH_STRIDE + (gy + w) * RSC + 4 * gx];
            const float4 q0 = *(const float4*)(rowp);
            const float4 q1 = *(const float4*)(rowp + 4);
            const float4 q2 = *(const float4*)(rowp + 8);
            const float v[12] = {q0.x, q0.y, q0.z, q0.w,
                                 q1.x, q1.y, q1.z, q1.w,
                                 q2.x, q2.y, q2.z, q2.w};
            const float a[4] = {a4.x, a4.y, a4.z, a4.w};
            #pragma unroll
            for (int dx = 0; dx < 9; ++dx)
                #pragma unroll
                for (int p = 0; p < 4; ++p)
                    acc[dx][p] += a[p] * v[dx + p];
        }
        // ---- commit prefetched chunk k+1 (LDS write after this iter's barrier: safe) ----
        if (k + 1 < NK) {
            const int lb = ((k + 1) & 1) * BUF_DW;
            #pragma unroll
            for (int s = 0; s < NSLOT; ++s)
                if (s_act[s]) *(float4*)(&stg[lb + s_loff[s]]) = nf[s];
            #pragma unroll
            for (int cl = 0; cl < CC; ++cl)
                a1[cl] = a1n[cl];
        }
    }

    // ---- epilogue: scale and store 9 aligned float4 per thread ----
    const float inv = 1.0f / (float)Cc;
    float* ob = out + (((size_t)bb * 81 + (3 * g + w) * 9) * Hc + (y0 + gy)) * Wc + x0 + 4 * gx;
    #pragma unroll
    for (int dx = 0; dx < 9; ++dx) {
        float4 st = make_float4(acc[dx][0] * inv, acc[dx][1] * inv,
                                acc[dx][2] * inv, acc[dx][3] * inv);
        *(float4*)(ob + dx * (Hc * Wc)) = st;
    }
}

extern "C" void kernel_launch(void* const* d_in, const int* in_sizes, int n_in,
                              void* d_out, int out_size, void* d_ws, size_t ws_size,
                              hipStream_t stream) {
    const float* x1 = (const float*)d_in[0];
    const float* x2 = (const float*)d_in[1];
    float* out = (float*)d_out;
    dim3 grid(3 * 8 * 8 * Bc), block(NTHR);   // 768 blocks x 192 threads
    corr_kernel<<<grid, block, 0, stream>>>(x1, x2, out);
}

// Round 4
// 201.125 us; speedup vs baseline: 1.6147x; 1.6147x over previous
//
#include <hip/hip_runtime.h>

// FlowNet correlation: out[b, dy*9+dx, y, x] = (1/256) sum_c x1[b,c,y,x] * x2[b,c,y+dy-4,x+dx-4]
// B=4 C=256 H=W=128, 9x9 displacements, zero padding.
//
// Round-4 = round-2 compute structure (validated: no spills, 137 us)
//         + round-3 XCD swizzle (validated: FETCH 464->188 MB).
// The round-3 x1 register prefetch is REVERTED (it spilled: WRITE_SIZE 21->58 MB).
//
//  - 3 d-groups (dy = 3g + wave_id), block = 192 thr = 3 waves, tile 16x16 px.
//  - Each wave computes ONE dy for ALL channels -> acc[9][4] = 36 regs, no reduction.
//  - x2 staged row-major, row stride 48 dw (48%32==16 -> conflict-free ds_read_b128).
//  - Double-buffered x2 staging, one barrier per 4-channel chunk.
//  - Swizzle: g-siblings of a tile get bids {base, base+8, base+16} -> same XCD L2.

#define MD 4
constexpr int Bc = 4, Cc = 256, Hc = 128, Wc = 128;
constexpr int TH = 16, TW = 16;
constexpr int NDY = 3;                  // dy per d-group (one per wave)
constexpr int CC = 4;                   // channels per chunk
constexpr int SROWS = TH + NDY - 1;     // 18 staged rows
constexpr int SCOLS = TW + 2 * MD;      // 24 staged cols
constexpr int RSC = 48;                 // padded row stride (dw)
constexpr int CH_STRIDE = SROWS * RSC;  // 864 dw per channel
constexpr int BUF_DW = CC * CH_STRIDE;  // 3456 dw per buffer
constexpr int NF4 = CC * SROWS * (SCOLS / 4);  // 432 float4 staging slots
constexpr int NTHR = 192;
constexpr int NSLOT = 3;                // ceil(432/192)
constexpr int NK = Cc / CC;             // 64 chunks

__global__ __launch_bounds__(NTHR, 4)
void corr_kernel(const float* __restrict__ x1, const float* __restrict__ x2,
                 float* __restrict__ out)
{
    __shared__ float stg[2 * BUF_DW];   // 27648 B

    const int tid  = threadIdx.x;
    const int w    = tid >> 6;          // wave id = local dy
    const int lane = tid & 63;
    const int gy   = lane >> 2;         // 0..15 tile row
    const int gx   = lane & 3;          // 0..3  col-group (4 px each)

    // ---- XCD-aware swizzle: g-siblings (same tile) differ by +8 in bid -> same XCD ----
    const int bid  = blockIdx.x;
    const int q    = bid / 24;
    const int r    = bid - q * 24;
    const int g    = r >> 3;            // d-group 0..2
    const int t    = q * 8 + (r & 7);   // tile index 0..255
    const int tx = t & 7;
    const int ty = (t >> 3) & 7;
    const int bb = t >> 6;
    const int x0 = tx * TW, y0 = ty * TH;
    const int rowbase = y0 + 3 * g - MD;   // global y of staged row 0

    // ---- hoisted staging slot descriptors (fixed per thread across chunks) ----
    int  s_goff[NSLOT], s_loff[NSLOT];
    bool s_val[NSLOT], s_act[NSLOT];
    #pragma unroll
    for (int s = 0; s < NSLOT; ++s) {
        int idx = tid + s * NTHR;
        bool active = idx < NF4;
        int i2  = active ? idx : 0;
        int cl  = i2 / (SROWS * 6);
        int rem = i2 - cl * (SROWS * 6);
        int rr  = rem / 6;
        int gc  = rem - rr * 6;
        int yy  = rowbase + rr;
        int xx  = x0 - 4 + 4 * gc;          // multiple of 4: float4 all-valid or all-invalid
        s_act[s]  = active;
        s_val[s]  = active && ((unsigned)yy < (unsigned)Hc) && ((unsigned)xx < (unsigned)(Wc - 3));
        s_goff[s] = cl * (Hc * Wc) + yy * Wc + xx;
        s_loff[s] = cl * CH_STRIDE + rr * RSC + 4 * gc;
    }

    const float* x2b = x2 + (size_t)bb * Cc * Hc * Wc;
    const float* x1b = x1 + (((size_t)bb * Cc) * Hc + (y0 + gy)) * Wc + x0 + 4 * gx;

    float acc[9][4];
    #pragma unroll
    for (int dx = 0; dx < 9; ++dx)
        #pragma unroll
        for (int p = 0; p < 4; ++p) acc[dx][p] = 0.f;

    const float4 f40 = make_float4(0.f, 0.f, 0.f, 0.f);
    float4 nf[NSLOT];

    // ---- prologue: stage chunk 0 into buffer 0 ----
    #pragma unroll
    for (int s = 0; s < NSLOT; ++s) {
        nf[s] = f40;
        if (s_val[s]) nf[s] = *(const float4*)(x2b + s_goff[s]);
    }
    #pragma unroll
    for (int s = 0; s < NSLOT; ++s)
        if (s_act[s]) *(float4*)(&stg[s_loff[s]]) = nf[s];

    for (int k = 0; k < NK; ++k) {
        const int pb = k & 1;
        // issue global x2 prefetch for chunk k+1 (latency overlapped with compute below)
        if (k + 1 < NK) {
            const int gof = (k + 1) * CC * Hc * Wc;
            #pragma unroll
            for (int s = 0; s < NSLOT; ++s) {
                nf[s] = f40;
                if (s_val[s]) nf[s] = *(const float4*)(x2b + gof + s_goff[s]);
            }
        }
        __syncthreads();   // chunk k's buffer fully written; prev buffer's readers done
        // ---- compute chunk k (x1 loaded inline: L1/L2 hits, no reg pressure) ----
        #pragma unroll
        for (int cl = 0; cl < CC; ++cl) {
            const int c = k * CC + cl;
            const float4 a4 = *(const float4*)(x1b + c * (Hc * Wc));
            const float* rowp = &stg[pb * BUF_DW + cl * CH_STRIDE + (gy + w) * RSC + 4 * gx];
            const float4 q0 = *(const float4*)(rowp);
            const float4 q1 = *(const float4*)(rowp + 4);
            const float4 q2 = *(const float4*)(rowp + 8);
            const float v[12] = {q0.x, q0.y, q0.z, q0.w,
                                 q1.x, q1.y, q1.z, q1.w,
                                 q2.x, q2.y, q2.z, q2.w};
            const float a[4] = {a4.x, a4.y, a4.z, a4.w};
            #pragma unroll
            for (int dx = 0; dx < 9; ++dx)
                #pragma unroll
                for (int p = 0; p < 4; ++p)
                    acc[dx][p] += a[p] * v[dx + p];
        }
        // ---- commit prefetched chunk k+1 (after this iter's barrier: safe) ----
        if (k + 1 < NK) {
            const int lb = ((k + 1) & 1) * BUF_DW;
            #pragma unroll
            for (int s = 0; s < NSLOT; ++s)
                if (s_act[s]) *(float4*)(&stg[lb + s_loff[s]]) = nf[s];
        }
    }

    // ---- epilogue: scale and store 9 aligned float4 per thread ----
    const float inv = 1.0f / (float)Cc;
    float* ob = out + (((size_t)bb * 81 + (3 * g + w) * 9) * Hc + (y0 + gy)) * Wc + x0 + 4 * gx;
    #pragma unroll
    for (int dx = 0; dx < 9; ++dx) {
        float4 st = make_float4(acc[dx][0] * inv, acc[dx][1] * inv,
                                acc[dx][2] * inv, acc[dx][3] * inv);
        *(float4*)(ob + dx * (Hc * Wc)) = st;
    }
}

extern "C" void kernel_launch(void* const* d_in, const int* in_sizes, int n_in,
                              void* d_out, int out_size, void* d_ws, size_t ws_size,
                              hipStream_t stream) {
    const float* x1 = (const float*)d_in[0];
    const float* x2 = (const float*)d_in[1];
    float* out = (float*)d_out;
    dim3 grid(3 * 8 * 8 * Bc), block(NTHR);   // 768 blocks x 192 threads
    corr_kernel<<<grid, block, 0, stream>>>(x1, x2, out);
}